// Round 10
// baseline (41.513 us; speedup 1.0000x reference)
//
#include <hip/hip_runtime.h>
#include <math.h>

#define OUT_H 7
#define OUT_W 7
#define NBINS 49
#define CCH   256
#define ELEMS (NBINS * CCH)    // 12544 outputs per box
#define KCH   7                // elements per thread: 7*256 = 1792, 7 blocks/box exact
// grid.x = 8 (multiple of 8): linear block id = x + 8*y -> XCD = x % 8,
// independent of box index y. Channel-slice x of EVERY box maps to the same
// XCD, so feature lines shared across overlapping boxes are fetched into one
// L2, not eight. (Round-4 win: FETCH 253 MB -> 90 MB.) Block x==7 exits.
#define GRIDX 8

typedef float f32x2 __attribute__((ext_vector_type(2)));
struct __attribute__((packed)) F2A { f32x2 v; } __attribute__((aligned(4)));

// ---------- fused kernel: per-block param compute + gather + blend ----------
// One block = 1792 consecutive output elements of one box (7 blocks/box).
// Threads 0..48 compute the 49 bilinear bin params into SoA LDS; then the
// R6-proven gather body: KCH statically-indexed register chunks -> 14 loads
// in flight per thread. R10: weights are NOT kept in registers — re-read
// from LDS in the blend loop (conflict-free, <=2-way) to cut ~28 VGPRs,
// targeting VGPR<=64 so launch_bounds(256,8) doubles resident waves
// (16 -> 32 waves/CU) and with them outstanding scattered loads.
__global__ __launch_bounds__(256, 8)
void msroi_fused_kernel(const float* __restrict__ f0,
                        const float* __restrict__ f1,
                        const float* __restrict__ f2,
                        const float* __restrict__ f3,
                        const float* __restrict__ boxes,
                        float* __restrict__ out,
                        int L)
{
    __shared__ unsigned so0[NBINS], so1[NBINS];
    __shared__ float    sw0[NBINS], sw1[NBINS], sw2[NBINS], sw3[NBINS];

    int bx = blockIdx.x;
    if (bx >= 7) return;                   // padded block (x==7): uniform exit
    int m   = blockIdx.y;                  // box (uniform per block)
    int tid = threadIdx.x;

    // --- block-uniform: box -> level -> plane geometry (every thread) ---
    float bx1 = boxes[m*4+0], by1 = boxes[m*4+1];
    float bx2 = boxes[m*4+2], by2 = boxes[m*4+3];

    float sz  = sqrtf((bx2 - bx1 + 1.0f) * (by2 - by1 + 1.0f));
    float lvf = floorf(4.0f + log2f(sz / 224.0f) + 1e-8f);
    lvf = fminf(fmaxf(lvf, 2.0f), 5.0f);
    int lv = (int)lvf - 2;

    const float* feat; int H, W; float scale;
    switch (lv) {
        case 0:  feat = f0; H = 256; W = 256; scale = 0.25f;    break;
        case 1:  feat = f1; H = 128; W = 128; scale = 0.125f;   break;
        case 2:  feat = f2; H = 64;  W = 64;  scale = 0.0625f;  break;
        default: feat = f3; H = 32;  W = 32;  scale = 0.03125f; break;
    }
    int b = m / L;
    const char* base = (const char*)(feat + (size_t)b * CCH * (size_t)(H * W));
    unsigned chanBytes = (unsigned)(H * W * 4);

    // --- threads 0..48: per-bin bilinear params into SoA LDS ---
    if (tid < NBINS) {
        int yh = tid / OUT_W;
        int xw = tid - yh * OUT_W;

        float x1 = bx1 * scale, y1 = by1 * scale;
        float x2 = bx2 * scale, y2 = by2 * scale;
        float roi_w = fmaxf(x2 - x1, 1.0f);
        float roi_h = fmaxf(y2 - y1, 1.0f);
        float bin_w = roi_w * (1.0f / OUT_W);
        float bin_h = roi_h * (1.0f / OUT_H);
        float sx = x1 + ((float)xw + 0.5f) * bin_w;
        float sy = y1 + ((float)yh + 0.5f) * bin_h;

        // _bilinear_axis(x): pair covers (xA, xA+1)
        bool  vx  = (sx >= -1.0f) && (sx <= (float)W);
        float scx = fmaxf(sx, 0.0f);
        int   xlr = (int)floorf(scx);
        bool  hxf = xlr >= (W - 1);
        float lx  = hxf ? 0.0f : (scx - (float)xlr);
        int   xA  = hxf ? (W - 2) : xlr;
        float wxA = hxf ? 0.0f : (1.0f - lx);
        float wxB = hxf ? 1.0f : lx;

        // _bilinear_axis(y): two row loads at rows rA, rB
        bool  vy  = (sy >= -1.0f) && (sy <= (float)H);
        float scy = fmaxf(sy, 0.0f);
        int   ylr = (int)floorf(scy);
        bool  hyf = ylr >= (H - 1);
        int   rA  = hyf ? (H - 1) : ylr;
        int   rB  = hyf ? (H - 1) : (ylr + 1);
        float ly  = hyf ? 0.0f : (scy - (float)ylr);
        float wyA = 1.0f - ly;
        float wyB = ly;

        float vmask = (vx && vy) ? 1.0f : 0.0f;

        so0[tid] = (unsigned)((rA * W + xA) * 4);
        so1[tid] = (unsigned)((rB * W + xA) * 4);
        sw0[tid] = vmask * wyA * wxA;
        sw1[tid] = vmask * wyA * wxB;
        sw2[tid] = vmask * wyB * wxA;
        sw3[tid] = vmask * wyB * wxB;
    }
    __syncthreads();

    // --- gather (loads only; weights stay in LDS to save VGPRs) ---
    int e_base = bx * (256 * KCH) + tid;   // e = e_base + k*256 < 12544 always

    f32x2 r0[KCH], r1[KCH];

    #pragma unroll
    for (int k = 0; k < KCH; ++k) {
        int e = e_base + k * 256;
        unsigned c   = (unsigned)e / NBINS;        // magic-mul div
        unsigned bin = (unsigned)e - c * NBINS;
        const char* plane = base + (unsigned long long)c
                                 * (unsigned long long)chanBytes;
        r0[k] = ((const F2A*)(plane + so0[bin]))->v;   // (vA0, vA1)
        r1[k] = ((const F2A*)(plane + so1[bin]))->v;   // (vB0, vB1)
    }

    // --- blend: re-read weights from LDS (conflict-free), NT store ---
    size_t outBase = (size_t)m * ELEMS + (size_t)e_base;
    #pragma unroll
    for (int k = 0; k < KCH; ++k) {
        int e = e_base + k * 256;
        unsigned c   = (unsigned)e / NBINS;
        unsigned bin = (unsigned)e - c * NBINS;
        float v = r0[k].x * sw0[bin] + r0[k].y * sw1[bin]
                + r1[k].x * sw2[bin] + r1[k].y * sw3[bin];
        __builtin_nontemporal_store(v, &out[outBase + (size_t)k * 256]);
    }
}

extern "C" void kernel_launch(void* const* d_in, const int* in_sizes, int n_in,
                              void* d_out, int out_size, void* d_ws, size_t ws_size,
                              hipStream_t stream) {
    const float* f0    = (const float*)d_in[0];
    const float* f1    = (const float*)d_in[1];
    const float* f2    = (const float*)d_in[2];
    const float* f3    = (const float*)d_in[3];
    const float* boxes = (const float*)d_in[4];
    float* out = (float*)d_out;

    const int N = 2;
    const int M = in_sizes[4] / 4;   // total boxes (N*L)
    const int L = M / N;             // boxes per batch

    dim3 grid(GRIDX, M);  // 7 active blocks/box (block 7 exits); XCD = x % 8
    msroi_fused_kernel<<<grid, 256, 0, stream>>>(f0, f1, f2, f3, boxes, out, L);
}